// Round 6
// baseline (7465.890 us; speedup 1.0000x reference)
//
#include <hip/hip_runtime.h>
#include <math.h>

#define NFULL 2177   // 1 + L + S
#define NN    2176   // minor size = 17*128
#define NMAT  8      // 4 batches x {z, target}
#define NBATCH 4
#define LDST  68     // LDS row stride (floats) for 64x64 tiles
#define FRAGM ((size_t)68 * 8 * 512)   // shorts per matrix per frag plane
#define GRIDB 512    // 2 blocks/CU x 256 CUs; co-resident by __launch_bounds__(256,2)

typedef unsigned int   u32;
typedef unsigned short u16;
typedef __attribute__((ext_vector_type(8)))  short short8;
typedef __attribute__((ext_vector_type(16))) float f32x16;

// ---------------- scalar helpers ----------------

__device__ inline void bf16split(float x, u16& hi, u16& lo) {
  u32 xb = __float_as_uint(x);
  u32 h = (xb + 0x7FFFu + ((xb >> 16) & 1u)) >> 16;
  float r = x - __uint_as_float(h << 16);
  u32 rb = __float_as_uint(r);
  u32 l2 = (rb + 0x7FFFu + ((rb >> 16) & 1u)) >> 16;
  hi = (u16)h; lo = (u16)l2;
}
__device__ inline void packstore(short* P, size_t off, const u16 v[8]) {
  *(uint4*)(P + off) = make_uint4(v[0] | ((u32)v[1] << 16), v[2] | ((u32)v[3] << 16),
                                  v[4] | ((u32)v[5] << 16), v[6] | ((u32)v[7] << 16));
}
__device__ inline f32x16 zero16() {
  f32x16 z;
#pragma unroll
  for (int i = 0; i < 16; ++i) z[i] = 0.f;
  return z;
}
__device__ inline f32x16 mfma3(short8 ah, short8 al, short8 bh, short8 bl, f32x16 c) {
  c = __builtin_amdgcn_mfma_f32_32x32x16_bf16(ah, bh, c, 0, 0, 0);
  c = __builtin_amdgcn_mfma_f32_32x32x16_bf16(ah, bl, c, 0, 0, 0);
  c = __builtin_amdgcn_mfma_f32_32x32x16_bf16(al, bh, c, 0, 0, 0);
  return c;
}
__device__ inline void split8(const float v[8], short8& h, short8& l) {
  u16 hh, ll;
#pragma unroll
  for (int j = 0; j < 8; ++j) { bf16split(v[j], hh, ll); h[j] = (short)hh; l[j] = (short)ll; }
}
__device__ inline void aop_lds(const float* X, int row, int kl, short8& h, short8& l) {
  const float* p = &X[row * LDST + kl];
  float4 a = *(const float4*)p, b = *(const float4*)(p + 4);
  float v[8] = {a.x, a.y, a.z, a.w, b.x, b.y, b.z, b.w};
  split8(v, h, l);
}
__device__ inline void bop_lds(const float* X, int col, int kl, short8& h, short8& l) {
  float v[8];
#pragma unroll
  for (int j = 0; j < 8; ++j) v[j] = X[(kl + j) * LDST + col];
  split8(v, h, l);
}
__device__ inline void pack_row(const float* X, int rowbase, int kl, int l,
                                short* Phi, short* Plo, size_t off) {
  const float* p = &X[(rowbase + (l & 31)) * LDST + kl];
  float4 a = *(const float4*)p, b = *(const float4*)(p + 4);
  float v[8] = {a.x, a.y, a.z, a.w, b.x, b.y, b.z, b.w};
  u16 hi[8], lo[8];
#pragma unroll
  for (int j = 0; j < 8; ++j) bf16split(v[j], hi[j], lo[j]);
  packstore(Phi, off, hi); packstore(Plo, off, lo);
}
__device__ inline void pack_col(const float* X, int colbase, int kl, int l,
                                short* Phi, short* Plo, size_t off) {
  int col = colbase + (l & 31);
  u16 hi[8], lo[8];
#pragma unroll
  for (int j = 0; j < 8; ++j) bf16split(X[(kl + j) * LDST + col], hi[j], lo[j]);
  packstore(Phi, off, hi); packstore(Plo, off, lo);
}

// ---------------- tile helpers ----------------

__device__ inline void load64(float* X, const float* A, int r0, int c0, int tid) {
#pragma unroll
  for (int it = 0; it < 4; ++it) {
    int f = tid + it * 256;
    int r = f >> 4, c4 = f & 15;
    *(float4*)&X[r * LDST + c4 * 4] = *(const float4*)&A[(size_t)(r0 + r) * NN + c0 + c4 * 4];
  }
}

__device__ inline void factor64(float* D, int tid) {
  for (int j = 0; j < 63; ++j) {
    float inv = 1.0f / D[j * LDST + j];
    for (int r = j + 1 + tid; r < 64; r += 256) D[r * LDST + j] *= inv;
    __syncthreads();
    int cc = j + 1 + (tid & 63);
    for (int rr = j + 1 + (tid >> 6); rr < 64; rr += 4)
      if (cc < 64) D[rr * LDST + cc] -= D[rr * LDST + j] * D[j * LDST + cc];
    __syncthreads();
  }
}

__device__ inline void inv_upper64(const float* S, float* V, float* scr, int tid) {
  if (tid < 64) {
    int o = (tid >> 5) * 32, j = tid & 31;
    V[(o + j) * LDST + o + j] = 1.0f / S[(o + j) * LDST + o + j];
    for (int i = j - 1; i >= 0; --i) {
      float a = 0.f;
      for (int t = i + 1; t <= j; ++t) a += S[(o + i) * LDST + o + t] * V[(o + t) * LDST + o + j];
      V[(o + i) * LDST + o + j] = -a / S[(o + i) * LDST + o + i];
    }
    for (int i = j + 1; i < 32; ++i) V[(o + i) * LDST + o + j] = 0.f;
  }
  for (int e = tid; e < 1024; e += 256) V[(32 + (e >> 5)) * LDST + (e & 31)] = 0.f;
  __syncthreads();
  for (int e = tid; e < 1024; e += 256) {
    int a = e >> 5, c = e & 31; float s = 0.f;
    for (int t = 0; t < 32; ++t) s += S[a * LDST + 32 + t] * V[(32 + t) * LDST + 32 + c];
    scr[a * 33 + c] = s;
  }
  __syncthreads();
  for (int e = tid; e < 1024; e += 256) {
    int a = e >> 5, c = e & 31; float s = 0.f;
    for (int t = 0; t < 32; ++t) s += V[a * LDST + t] * scr[t * 33 + c];
    V[a * LDST + 32 + c] = -s;
  }
  __syncthreads();
}

__device__ inline void inv_lower64(const float* S, float* V, float* scr, int tid) {
  if (tid < 64) {
    int o = (tid >> 5) * 32, j = tid & 31;
    V[(o + j) * LDST + o + j] = 1.0f;
    for (int i = j + 1; i < 32; ++i) {
      float a = 0.f;
      for (int t = j; t < i; ++t) a += S[(o + i) * LDST + o + t] * V[(o + t) * LDST + o + j];
      V[(o + i) * LDST + o + j] = -a;
    }
    for (int i = 0; i < j; ++i) V[(o + i) * LDST + o + j] = 0.f;
  }
  for (int e = tid; e < 1024; e += 256) V[(e >> 5) * LDST + 32 + (e & 31)] = 0.f;
  __syncthreads();
  for (int e = tid; e < 1024; e += 256) {
    int a = e >> 5, c = e & 31; float s = 0.f;
    for (int t = 0; t < 32; ++t) s += S[(32 + a) * LDST + t] * V[t * LDST + c];
    scr[a * 33 + c] = s;
  }
  __syncthreads();
  for (int e = tid; e < 1024; e += 256) {
    int a = e >> 5, c = e & 31; float s = 0.f;
    for (int t = 0; t < 32; ++t) s += V[(32 + a) * LDST + 32 + t] * scr[t * 33 + c];
    V[(32 + a) * LDST + c] = -s;
  }
  __syncthreads();
}

__device__ inline void logdet64(const float* X, double* dst, int tid, float* scr) {
  __syncthreads();
  if (tid < 64) scr[tid] = logf(fabsf(X[tid * LDST + tid]));
  __syncthreads();
  if (tid == 0) {
    double s = 0.0;
    for (int i = 0; i < 64; ++i) s += (double)scr[i];
    atomicAdd(dst, s);
  }
  __syncthreads();
}

__device__ inline void acc_to_lds(float* Y, int rt, int ct, int l, const f32x16& a) {
  int lr = 4 * (l >> 5), lc = l & 31;
#pragma unroll
  for (int reg = 0; reg < 16; ++reg) {
    int ro = lr + (reg & 3) + 8 * (reg >> 2);
    Y[(rt * 32 + ro) * LDST + ct * 32 + lc] = a[reg];
  }
}
__device__ inline void rmw_tile(float* __restrict__ A, int R0, int C0, const f32x16& ac) {
#pragma unroll
  for (int reg = 0; reg < 16; ++reg) {
    int row = R0 + (reg & 3) + 8 * (reg >> 2);
    A[(size_t)row * NN + C0] -= ac[reg];
  }
}
__device__ inline void dstage(const float* A, int gR, int gC, int lR, int lC,
                              const f32x16& a, float* X, int lr, int lc) {
#pragma unroll
  for (int reg = 0; reg < 16; ++reg) {
    int ro = lr + (reg & 3) + 8 * (reg >> 2);
    X[(lR + ro) * LDST + lC + lc] = A[(size_t)(gR + ro) * NN + gC + lc] - a[reg];
  }
}

__device__ inline void packA64(const float* Y, short* Phi, short* Plo,
                               size_t pb, int tG0, int s0, int tid) {
  for (int f = tid; f < 512; f += 256) {
    int l = f & 63, sl = (f >> 6) & 3, tt = (f >> 8) & 1;
    int kl = sl * 16 + (l >> 5) * 8;
    size_t off = pb + (((size_t)(tG0 + tt) * 8 + s0 + sl) * 512 + (size_t)l * 8);
    pack_row(Y, tt * 32, kl, l, Phi, Plo, off);
  }
}
__device__ inline void packB64(const float* Y, short* Phi, short* Plo,
                               size_t pb, int tG0, int s0, int tid) {
  for (int f = tid; f < 512; f += 256) {
    int l = f & 63, sl = (f >> 6) & 3, tt = (f >> 8) & 1;
    int kl = sl * 16 + (l >> 5) * 8;
    size_t off = pb + (((size_t)(tG0 + tt) * 8 + s0 + sl) * 512 + (size_t)l * 8);
    pack_col(Y, tt * 32, kl, l, Phi, Plo, off);
  }
}
__device__ inline size_t ivoff(int m, int slot, int tt, int s, int l) {
  return (((size_t)(m * 2 + slot) * 2 + tt) * 4 + s) * 512 + (size_t)l * 8;
}
__device__ inline void packInvB(const float* Y, short* Phi, short* Plo, int m, int slot, int tid) {
  for (int f = tid; f < 512; f += 256) {
    int l = f & 63, sl = (f >> 6) & 3, tt = (f >> 8) & 1;
    int kl = sl * 16 + (l >> 5) * 8;
    pack_col(Y, tt * 32, kl, l, Phi, Plo, ivoff(m, slot, tt, sl, l));
  }
}
__device__ inline void packInvA(const float* Y, short* Phi, short* Plo, int m, int slot, int tid) {
  for (int f = tid; f < 512; f += 256) {
    int l = f & 63, sl = (f >> 6) & 3, tt = (f >> 8) & 1;
    int kl = sl * 16 + (l >> 5) * 8;
    pack_row(Y, tt * 32, kl, l, Phi, Plo, ivoff(m, slot, tt, sl, l));
  }
}

// software grid barrier: generation-counted atomic + device-scope fences.
// Correct for co-resident grids (guaranteed by __launch_bounds__(256,2), grid=512).
__device__ inline void gsync(u32* bar, u32* gen) {
  __syncthreads();
  if (threadIdx.x == 0) {
    __threadfence();                       // release: drain + make stores visible
    u32 g = ++(*gen);
    atomicAdd(bar, 1u);                    // device-scope arrive
    u32 target = g * (u32)GRIDB;
    long long guard = 0;
    while (__hip_atomic_load(bar, __ATOMIC_RELAXED, __HIP_MEMORY_SCOPE_AGENT) < target) {
      if (++guard > 1000000000LL) break;   // bail out instead of hanging the harness
    }
    __threadfence();                       // acquire: invalidate stale cache
  }
  __syncthreads();
}

// ---------------- build phase ----------------

__global__ void init_kernel(float* __restrict__ cs, double* __restrict__ dlog,
                            u32* __restrict__ bar) {
  int i = blockIdx.x * blockDim.x + threadIdx.x;
  if (i < NMAT * NN) cs[i] = 0.f;
  if (i < NMAT) dlog[i] = 0.0;
  if (i == 0) bar[0] = 0u;
}

__global__ __launch_bounds__(256) void build_kernel(
    const float* __restrict__ scores, const float* __restrict__ zm,
    const float* __restrict__ tm, const int* __restrict__ lengths,
    float* __restrict__ M, float* __restrict__ cs) {
  int c = blockIdx.x * 256 + threadIdx.x;
  if (c >= NN) return;
  int b = blockIdx.z;
  int len = lengths[b];
  int j = c + 1;
  bool jv = (j < len);
  int r0 = blockIdx.y * 16;
  size_t sbase = (size_t)b * NFULL * NFULL;
  float* Mz = M + (size_t)b * NN * NN;
  float* Mt = M + (size_t)(NBATCH + b) * NN * NN;
  float az = 0.f, at = 0.f;
  for (int rr = 0; rr < 16; ++rr) {
    int r = r0 + rr, i = r + 1;
    float vz = 0.f, vt = 0.f;
    if (jv && i < len) {
      size_t off = sbase + (size_t)i * NFULL + j;
      float e = __expf(scores[off]);
      vz = e * zm[off];
      vt = e * tm[off];
    }
    Mz[(size_t)r * NN + c] = -vz;
    Mt[(size_t)r * NN + c] = -vt;
    az += vz; at += vt;
  }
  atomicAdd(&cs[b * NN + c], az);
  atomicAdd(&cs[(NBATCH + b) * NN + c], at);
}

__global__ void diag_fix_kernel(const float* __restrict__ scores,
                                const float* __restrict__ zm,
                                const float* __restrict__ tm,
                                const int* __restrict__ lengths,
                                const float* __restrict__ cs,
                                float* __restrict__ M) {
  int c = blockIdx.x * 256 + threadIdx.x;
  if (c >= NN) return;
  int m = blockIdx.y;
  int b = m & 3;
  const float* msk = (m < NBATCH) ? zm : tm;
  int len = lengths[b];
  int j = c + 1;
  float w0 = 0.f, pad = 1.f;
  if (j < len) {
    size_t off = (size_t)b * NFULL * NFULL + j;
    w0 = __expf(scores[off]) * msk[off];
    pad = 0.f;
  }
  M[(size_t)m * NN * NN + (size_t)c * NN + c] = cs[m * NN + c] + w0 + pad;
}

// ---------------- the whole LU in one kernel (software grid barrier) ----------------

__global__ __launch_bounds__(256, 2) void lu_coop(
    float* __restrict__ M,
    short* __restrict__ Ahi, short* __restrict__ Alo,
    short* __restrict__ Bhi, short* __restrict__ Blo,
    short* __restrict__ IAhi, short* __restrict__ IAlo,
    short* __restrict__ IBhi, short* __restrict__ IBlo,
    double* __restrict__ dlog, float* __restrict__ out, u32* __restrict__ bar) {
  __shared__ float X[64 * LDST];
  __shared__ float Y[64 * LDST];
  __shared__ float scr[32 * 33];
  __shared__ u32 gen_s;
  int tid = threadIdx.x;
  if (tid == 0) gen_s = 0u;
  int nb = GRIDB, bid = blockIdx.x;
  int w = tid >> 6, l = tid & 63;
  int lr = 4 * (l >> 5), lc = l & 31;

  // P0: factor D0 of each matrix, logdet, inverses -> slot0 frags
  for (int m = bid; m < NMAT; m += nb) {
    float* A = M + (size_t)m * NN * NN;
    load64(X, A, 0, 0, tid);
    __syncthreads();
    factor64(X, tid);
    logdet64(X, &dlog[m], tid, scr);
    inv_upper64(X, Y, scr, tid);
    packInvB(Y, IBhi, IBlo, m, 0, tid);
    __syncthreads();
    inv_lower64(X, Y, scr, tid);
    packInvA(Y, IAhi, IAlo, m, 0, tid);
    __syncthreads();
  }
  gsync(bar, &gen_s);

  for (int k0 = 0; k0 < NN - 64; k0 += 128) {
    int rem  = NN - k0 - 64;
    int rem2 = NN - k0 - 128;
    int nch  = rem / 64;
    int rt = w >> 1, ct = w & 1;

    // ---- P1: L-slab0 (rows>=k0+64 x invU00) + U-apply (invL00 x cols>=k0+64) ----
    {
      int njob = 2 * nch * NMAT;
      for (int job = bid; job < njob; job += nb) {
        int m = job % NMAT, jt = job / NMAT;
        float* A = M + (size_t)m * NN * NN;
        size_t pb = (size_t)m * FRAGM;
        if (jt < nch) {
          int r0 = k0 + 64 + 64 * jt;
          load64(X, A, r0, k0, tid);
          __syncthreads();
          f32x16 acc = zero16();
#pragma unroll
          for (int s = 0; s < 4; ++s) {
            short8 ah, al, bh, bl;
            aop_lds(X, rt * 32 + lc, s * 16 + (l >> 5) * 8, ah, al);
            size_t io = ivoff(m, 0, ct, s, l);
            bh = *(const short8*)(IBhi + io); bl = *(const short8*)(IBlo + io);
            acc = mfma3(ah, al, bh, bl, acc);
          }
          __syncthreads();
          acc_to_lds(Y, rt, ct, l, acc);
          __syncthreads();
          packA64(Y, Ahi, Alo, pb, r0 >> 5, 0, tid);
          __syncthreads();
        } else {
          int c0 = k0 + 64 + 64 * (jt - nch);
          load64(X, A, k0, c0, tid);      // T0 as [k][col]
          __syncthreads();
          f32x16 acc = zero16();
#pragma unroll
          for (int s = 0; s < 4; ++s) {
            short8 ah, al, bh, bl;
            size_t io = ivoff(m, 0, rt, s, l);
            ah = *(const short8*)(IAhi + io); al = *(const short8*)(IAlo + io);
            bop_lds(X, ct * 32 + lc, s * 16 + (l >> 5) * 8, bh, bl);
            acc = mfma3(ah, al, bh, bl, acc);
          }
          __syncthreads();
          acc_to_lds(Y, rt, ct, l, acc);
          __syncthreads();
          packB64(Y, Bhi, Blo, pb, c0 >> 5, 0, tid);
          __syncthreads();
        }
      }
    }
    gsync(bar, &gen_s);

    // ---- P2: 64-wide strip update (cols k0+64..k0+128) + factor D1 + inv slot1 ----
    {
      int njob = nch * NMAT;
      int tb = (k0 + 64) >> 5;
      for (int job = bid; job < njob; job += nb) {
        int m = job % NMAT, j = job / NMAT;
        float* A = M + (size_t)m * NN * NN;
        size_t pb = (size_t)m * FRAGM;
        int r0 = k0 + 64 + 64 * j;
        f32x16 acc = zero16();
#pragma unroll
        for (int s = 0; s < 4; ++s) {
          size_t oa = pb + (((size_t)((r0 >> 5) + rt) * 8 + s) * 512 + (size_t)l * 8);
          size_t ob = pb + (((size_t)(tb + ct) * 8 + s) * 512 + (size_t)l * 8);
          short8 ah = *(const short8*)(Ahi + oa), al = *(const short8*)(Alo + oa);
          short8 bh = *(const short8*)(Bhi + ob), bl = *(const short8*)(Blo + ob);
          acc = mfma3(ah, al, bh, bl, acc);
        }
        if (j > 0) {
          rmw_tile(A, r0 + rt * 32 + lr, k0 + 64 + ct * 32 + lc, acc);
        } else {
          dstage(A, r0 + rt * 32, k0 + 64 + ct * 32, rt * 32, ct * 32, acc, X, lr, lc);
          __syncthreads();
          factor64(X, tid);
          logdet64(X, &dlog[m], tid, scr);
          inv_upper64(X, Y, scr, tid);
          packInvB(Y, IBhi, IBlo, m, 1, tid);
          __syncthreads();
          inv_lower64(X, Y, scr, tid);
          packInvA(Y, IAhi, IAlo, m, 1, tid);
          __syncthreads();
        }
      }
    }
    gsync(bar, &gen_s);

    if (rem2 > 0) {
      // ---- P3: L-slab1 + U12 second 64 rows ----
      {
        int nch2 = rem2 / 64;
        int njob = 2 * nch2 * NMAT;
        int tl1 = (k0 + 64) >> 5;
        for (int job = bid; job < njob; job += nb) {
          int m = job % NMAT, jt = job / NMAT;
          float* A = M + (size_t)m * NN * NN;
          size_t pb = (size_t)m * FRAGM;
          if (jt < nch2) {
            int r0 = k0 + 128 + 64 * jt;
            load64(X, A, r0, k0 + 64, tid);   // A21' (post-P2)
            __syncthreads();
            f32x16 acc = zero16();
#pragma unroll
            for (int s = 0; s < 4; ++s) {
              short8 ah, al, bh, bl;
              aop_lds(X, rt * 32 + lc, s * 16 + (l >> 5) * 8, ah, al);
              size_t io = ivoff(m, 1, ct, s, l);
              bh = *(const short8*)(IBhi + io); bl = *(const short8*)(IBlo + io);
              acc = mfma3(ah, al, bh, bl, acc);
            }
            __syncthreads();
            acc_to_lds(Y, rt, ct, l, acc);
            __syncthreads();
            packA64(Y, Ahi, Alo, pb, r0 >> 5, 4, tid);
            __syncthreads();
          } else {
            int c0 = k0 + 128 + 64 * (jt - nch2);
            f32x16 acc = zero16();            // L10 * U0c
#pragma unroll
            for (int s = 0; s < 4; ++s) {
              size_t oa = pb + (((size_t)(tl1 + rt) * 8 + s) * 512 + (size_t)l * 8);
              size_t ob = pb + (((size_t)((c0 >> 5) + ct) * 8 + s) * 512 + (size_t)l * 8);
              short8 ah = *(const short8*)(Ahi + oa), al = *(const short8*)(Alo + oa);
              short8 bh = *(const short8*)(Bhi + ob), bl = *(const short8*)(Blo + ob);
              acc = mfma3(ah, al, bh, bl, acc);
            }
            load64(X, A, k0 + 64, c0, tid);   // T1
            __syncthreads();
#pragma unroll
            for (int reg = 0; reg < 16; ++reg) {
              int ro = lr + (reg & 3) + 8 * (reg >> 2);
              X[(rt * 32 + ro) * LDST + ct * 32 + lc] -= acc[reg];
            }
            __syncthreads();
            f32x16 a2 = zero16();             // U1 = invL11 * T1'
#pragma unroll
            for (int s = 0; s < 4; ++s) {
              short8 ah, al, bh, bl;
              size_t io = ivoff(m, 1, rt, s, l);
              ah = *(const short8*)(IAhi + io); al = *(const short8*)(IAlo + io);
              bop_lds(X, ct * 32 + lc, s * 16 + (l >> 5) * 8, bh, bl);
              a2 = mfma3(ah, al, bh, bl, a2);
            }
            __syncthreads();
            acc_to_lds(Y, rt, ct, l, a2);
            __syncthreads();
            packB64(Y, Bhi, Blo, pb, c0 >> 5, 4, tid);
            __syncthreads();
          }
        }
      }
      gsync(bar, &gen_s);

      // ---- P4: big trailing update K=128 + fused next D0 factor/inv ----
      {
        int nt = rem2 / 128;
        int njob = nt * nt * NMAT;
        int tbase = (k0 + 128) >> 5;
        for (int job = bid; job < njob; job += nb) {
          int m = job % NMAT, t = job / NMAT;
          int by = t / nt, bx = t % nt;
          float* A = M + (size_t)m * NN * NN;
          size_t pb = (size_t)m * FRAGM;
          int wr = w >> 1, wc = w & 1;
          int tr = tbase + by * 4 + wr * 2;
          int tc = tbase + bx * 4 + wc * 2;
          f32x16 acc[2][2];
          acc[0][0] = zero16(); acc[0][1] = zero16();
          acc[1][0] = zero16(); acc[1][1] = zero16();
#pragma unroll
          for (int s = 0; s < 8; ++s) {
            short8 ah[2], al[2], bh[2], bl[2];
#pragma unroll
            for (int t2 = 0; t2 < 2; ++t2) {
              size_t oa = pb + (((size_t)(tr + t2) * 8 + s) * 512 + (size_t)l * 8);
              ah[t2] = *(const short8*)(Ahi + oa); al[t2] = *(const short8*)(Alo + oa);
              size_t ob = pb + (((size_t)(tc + t2) * 8 + s) * 512 + (size_t)l * 8);
              bh[t2] = *(const short8*)(Bhi + ob); bl[t2] = *(const short8*)(Blo + ob);
            }
#pragma unroll
            for (int i = 0; i < 2; ++i)
#pragma unroll
              for (int j2 = 0; j2 < 2; ++j2)
                acc[i][j2] = mfma3(ah[i], al[i], bh[j2], bl[j2], acc[i][j2]);
          }
          bool corner = (bx == 0 && by == 0);
          if (!corner || w != 0) {
#pragma unroll
            for (int i = 0; i < 2; ++i)
#pragma unroll
              for (int j2 = 0; j2 < 2; ++j2)
                rmw_tile(A, (tr + i) * 32 + lr, (tc + j2) * 32 + lc, acc[i][j2]);
          } else {
            // wave0 of corner job: stage next D0' = old - acc into X (no global write)
#pragma unroll
            for (int i = 0; i < 2; ++i)
#pragma unroll
              for (int j2 = 0; j2 < 2; ++j2)
                dstage(A, (tr + i) * 32, (tc + j2) * 32, i * 32, j2 * 32, acc[i][j2], X, lr, lc);
          }
          if (corner) {
            __syncthreads();
            factor64(X, tid);
            logdet64(X, &dlog[m], tid, scr);
            inv_upper64(X, Y, scr, tid);
            packInvB(Y, IBhi, IBlo, m, 0, tid);
            __syncthreads();
            inv_lower64(X, Y, scr, tid);
            packInvA(Y, IAhi, IAlo, m, 0, tid);
            __syncthreads();
          }
        }
      }
      gsync(bar, &gen_s);
    }
  }

  gsync(bar, &gen_s);
  if (bid == 0 && tid == 0) {
    double s = 0.0;
    for (int b = 0; b < NBATCH; ++b) s += dlog[b] - dlog[NBATCH + b];
    out[0] = (float)(s * 0.25);
  }
}

// ---------------- launch ----------------

extern "C" void kernel_launch(void* const* d_in, const int* in_sizes, int n_in,
                              void* d_out, int out_size, void* d_ws, size_t ws_size,
                              hipStream_t stream) {
  const float* scores  = (const float*)d_in[0];
  const float* tm      = (const float*)d_in[1];
  const float* zm      = (const float*)d_in[2];
  const int*   lengths = (const int*)d_in[3];
  float* out = (float*)d_out;

  char* p = (char*)d_ws;
  float* M = (float*)p;      p += (size_t)NMAT * NN * NN * sizeof(float);
  short* Ahi = (short*)p;    p += NMAT * FRAGM * sizeof(short);
  short* Alo = (short*)p;    p += NMAT * FRAGM * sizeof(short);
  short* Bhi = (short*)p;    p += NMAT * FRAGM * sizeof(short);
  short* Blo = (short*)p;    p += NMAT * FRAGM * sizeof(short);
  size_t ivsz = (size_t)NMAT * 2 * 2 * 4 * 512;
  short* IAhi = (short*)p;   p += ivsz * sizeof(short);
  short* IAlo = (short*)p;   p += ivsz * sizeof(short);
  short* IBhi = (short*)p;   p += ivsz * sizeof(short);
  short* IBlo = (short*)p;   p += ivsz * sizeof(short);
  float* cs = (float*)p;     p += (size_t)NMAT * NN * sizeof(float);
  double* dlog = (double*)p; p += (size_t)NMAT * sizeof(double);
  u32* bar = (u32*)p;

  init_kernel<<<(NMAT * NN + 255) / 256, 256, 0, stream>>>(cs, dlog, bar);
  build_kernel<<<dim3((NN + 255) / 256, NN / 16, NBATCH), 256, 0, stream>>>(
      scores, zm, tm, lengths, M, cs);
  diag_fix_kernel<<<dim3((NN + 255) / 256, NMAT), 256, 0, stream>>>(
      scores, zm, tm, lengths, cs, M);
  lu_coop<<<GRIDB, 256, 0, stream>>>(M, Ahi, Alo, Bhi, Blo,
                                     IAhi, IAlo, IBhi, IBlo, dlog, out, bar);
}